// Round 1
// 488.000 us; speedup vs baseline: 1.0286x; 1.0286x over previous
//
#include <hip/hip_runtime.h>
#include <hip/hip_bf16.h>
#include <type_traits>

#define BATCH 2
#define SEQ   8192
#define CH    1024
#define NH    16
#define BLK   64
#define WIN   192
#define NBL   128
#define DH    64
#define MR    (BATCH*SEQ)   // 16384

typedef __bf16 bf16x8 __attribute__((ext_vector_type(8)));
typedef float  f32x4  __attribute__((ext_vector_type(4)));

__device__ __forceinline__ f32x4 zero4() {
    f32x4 z; z[0]=0.f; z[1]=0.f; z[2]=0.f; z[3]=0.f; return z;
}

union Pack8 { __hip_bfloat16 h[8]; uint4 u; };

typedef const __attribute__((address_space(1))) unsigned int* gas_ptr;
typedef       __attribute__((address_space(3))) unsigned int* las_ptr;

__device__ __forceinline__ void gload_lds16(const __hip_bfloat16* g, __hip_bfloat16* l) {
    __builtin_amdgcn_global_load_lds((gas_ptr)(const void*)g, (las_ptr)(void*)l, 16, 0, 0);
}

// Chunked XCD swizzle (T1): HW round-robins consecutive block ids over the 8
// XCDs, so the 8 N-tiles sharing one A-panel land on 8 different L2s (zero
// reuse). Remap so XCD k owns a contiguous chunk of logical tiles. Bijective
// iff nwg % 8 == 0 (all our grids: 1024, 2048/z-slice, 4096).
__device__ __forceinline__ int xcd_swz(int bid, int nwg) {
    return (bid & 7) * (nwg >> 3) + (bid >> 3);
}

// ---- fp32 -> bf16 pack, 8 elements/thread
__global__ __launch_bounds__(256) void pack_bf16(
    const float* __restrict__ src, __hip_bfloat16* __restrict__ dst, int n8)
{
    int i = blockIdx.x * 256 + threadIdx.x;
    if (i >= n8) return;
    const float4* s = reinterpret_cast<const float4*>(src);
    float4 a = s[2 * i], b = s[2 * i + 1];
    Pack8 p;
    p.h[0] = __float2bfloat16(a.x); p.h[1] = __float2bfloat16(a.y);
    p.h[2] = __float2bfloat16(a.z); p.h[3] = __float2bfloat16(a.w);
    p.h[4] = __float2bfloat16(b.x); p.h[5] = __float2bfloat16(b.y);
    p.h[6] = __float2bfloat16(b.z); p.h[7] = __float2bfloat16(b.w);
    reinterpret_cast<uint4*>(dst)[i] = p.u;
}

// ---- GEMM body: C[M,N] = alpha*(A @ Wb^T + bias); 128x128 tile, BK=64,
// global_load_lds width-16 into XOR-swizzled linear LDS (conflict-free b128
// reads despite the lane-contiguous write constraint). K = N = CH.
// m0/n0 are the (already-swizzled) tile origins.
template<typename OT>
__device__ __forceinline__ void gemm_body(
    const __hip_bfloat16* __restrict__ A, const __hip_bfloat16* __restrict__ Wb,
    const float* __restrict__ bias, OT* __restrict__ out, float alpha,
    int m0, int n0,
    __hip_bfloat16* As, __hip_bfloat16* Bs)
{
    const int tid  = threadIdx.x;
    const int wid  = tid >> 6;
    const int lane = tid & 63;
    const int quad = lane >> 4;
    const int l16  = lane & 15;
    const int wr   = wid >> 1, wc = wid & 1;

    // staging map: LDS chunk c (16B) holds row r=c>>3, global seg s=(c&7)^(r&7)
    int offA[4], offB[4];
    #pragma unroll
    for (int it = 0; it < 4; it++) {
        int c = tid + it * 256;
        int r = c >> 3;
        int s = (c & 7) ^ (r & 7);
        offA[it] = (m0 + r) * CH + s * 8;
        offB[it] = (n0 + r) * CH + s * 8;
    }

    f32x4 acc[4][4];
    #pragma unroll
    for (int i = 0; i < 4; i++)
        #pragma unroll
        for (int j = 0; j < 4; j++) acc[i][j] = zero4();

    for (int k0 = 0; k0 < CH; k0 += 64) {
        #pragma unroll
        for (int it = 0; it < 4; it++)
            gload_lds16(A + offA[it] + k0, As + (tid + it * 256) * 8);
        #pragma unroll
        for (int it = 0; it < 4; it++)
            gload_lds16(Wb + offB[it] + k0, Bs + (tid + it * 256) * 8);
        __syncthreads();

        #pragma unroll
        for (int kk = 0; kk < 2; kk++) {
            bf16x8 af[4], bfr[4];
            #pragma unroll
            for (int i = 0; i < 4; i++) {
                int r = wr * 64 + i * 16 + l16;
                int chunk = r * 8 + ((kk * 4 + quad) ^ (l16 & 7));
                af[i] = *reinterpret_cast<const bf16x8*>(As + chunk * 8);
            }
            #pragma unroll
            for (int j = 0; j < 4; j++) {
                int r = wc * 64 + j * 16 + l16;
                int chunk = r * 8 + ((kk * 4 + quad) ^ (l16 & 7));
                bfr[j] = *reinterpret_cast<const bf16x8*>(Bs + chunk * 8);
            }
            #pragma unroll
            for (int i = 0; i < 4; i++)
                #pragma unroll
                for (int j = 0; j < 4; j++)
                    acc[i][j] = __builtin_amdgcn_mfma_f32_16x16x32_bf16(
                        af[i], bfr[j], acc[i][j], 0, 0, 0);
        }
        __syncthreads();
    }

    #pragma unroll
    for (int j = 0; j < 4; j++) {
        const int col = n0 + wc * 64 + j * 16 + l16;
        const float bv = bias[col];
        #pragma unroll
        for (int i = 0; i < 4; i++) {
            #pragma unroll
            for (int r = 0; r < 4; r++) {
                const int row = m0 + wr * 64 + i * 16 + quad * 4 + r;
                float v = alpha * (acc[i][j][r] + bv);
                if constexpr (std::is_same<OT, float>::value)
                    out[(size_t)row * CH + col] = v;
                else
                    out[(size_t)row * CH + col] = __float2bfloat16(v);
            }
        }
    }
}

// Swizzled tile coords for the (8 x 128) per-slice grid. The z dim of gemm_qk
// contributes 1024 to the HW linear id (1024 % 8 == 0), so per-slice swizzle
// keeps the id%8 -> XCD correspondence.
__device__ __forceinline__ void gemm_tile(int& m0, int& n0) {
    int bid = blockIdx.y * 8 + blockIdx.x;       // per-slice linear id
    int swz = xcd_swz(bid, 1024);                // 128 tiles per XCD chunk
    m0 = (swz >> 3) * 128;                       // 16 consecutive M-panels/XCD
    n0 = (swz & 7) * 128;                        // x all 8 N-tiles -> 8x A reuse in L2
}

// Batched Q+K projections (blockIdx.z selects operand set).
__global__ __launch_bounds__(256) void gemm_qk(
    const __hip_bfloat16* __restrict__ A0, const __hip_bfloat16* __restrict__ W0,
    const float* __restrict__ b0, __hip_bfloat16* __restrict__ o0, float alpha0,
    const __hip_bfloat16* __restrict__ A1, const __hip_bfloat16* __restrict__ W1,
    const float* __restrict__ b1, __hip_bfloat16* __restrict__ o1)
{
    __shared__ alignas(16) __hip_bfloat16 As[128 * 64];
    __shared__ alignas(16) __hip_bfloat16 Bs[128 * 64];
    int m0, n0; gemm_tile(m0, n0);
    if (blockIdx.z == 0)
        gemm_body<__hip_bfloat16>(A0, W0, b0, o0, alpha0, m0, n0, As, Bs);
    else
        gemm_body<__hip_bfloat16>(A1, W1, b1, o1, 1.0f, m0, n0, As, Bs);
}

template<typename OT>
__global__ __launch_bounds__(256) void gemm_one(
    const __hip_bfloat16* __restrict__ A, const __hip_bfloat16* __restrict__ Wb,
    const float* __restrict__ bias, OT* __restrict__ out)
{
    __shared__ alignas(16) __hip_bfloat16 As[128 * 64];
    __shared__ alignas(16) __hip_bfloat16 Bs[128 * 64];
    int m0, n0; gemm_tile(m0, n0);
    gemm_body<OT>(A, Wb, bias, out, 1.0f, m0, n0, As, Bs);
}

// One workgroup per (b, h, block-of-64-queries). Window of 192 keys
// starting at t0-64 (clamped loads, analytic masking).
__global__ __launch_bounds__(256) void attn_kernel(
    const __hip_bfloat16* __restrict__ qg,
    const __hip_bfloat16* __restrict__ kg,
    const __hip_bfloat16* __restrict__ vg,
    __hip_bfloat16* __restrict__ ctx)
{
    __shared__ alignas(16) char smem[62464];
    auto qs = reinterpret_cast<__hip_bfloat16(*)[72]>(smem);
    auto ks = reinterpret_cast<__hip_bfloat16(*)[72]>(smem + 9216);
    auto vt = reinterpret_cast<__hip_bfloat16(*)[200]>(smem + 36864);
    auto ps = reinterpret_cast<__hip_bfloat16(*)[200]>(smem);

    // XCD-chunked swizzle: adjacent n-blocks share 128/192 of their K/V window;
    // keep them on the same XCD L2. Each XCD chunk = full n-range of 4 heads.
    const int blk = xcd_swz(blockIdx.x, BATCH * NH * NBL);
    const int n = blk & (NBL - 1);
    const int h = (blk >> 7) & (NH - 1);
    const int b = blk >> 11;
    const int t0  = n * BLK;
    const int kst = t0 - 64;
    const int tid = threadIdx.x;
    const size_t baseBH = (size_t)b * SEQ * CH + (size_t)h * DH;

    #pragma unroll
    for (int it = 0; it < 2; it++) {
        int c = tid + it * 256;
        int row = c >> 3, seg = c & 7;
        *reinterpret_cast<uint4*>(&qs[row][seg * 8]) =
            *reinterpret_cast<const uint4*>(qg + baseBH + (size_t)(t0 + row) * CH + seg * 8);
    }
    #pragma unroll
    for (int it = 0; it < 6; it++) {
        int c = tid + it * 256;
        int row = c >> 3, seg = c & 7;
        int tr = kst + row; tr = tr < 0 ? 0 : (tr >= SEQ ? SEQ - 1 : tr);
        *reinterpret_cast<uint4*>(&ks[row][seg * 8]) =
            *reinterpret_cast<const uint4*>(kg + baseBH + (size_t)tr * CH + seg * 8);
    }
    #pragma unroll
    for (int it = 0; it < 6; it++) {
        int c = tid + it * 256;
        int j = c % WIN, seg = c / WIN;
        int tr = kst + j; tr = tr < 0 ? 0 : (tr >= SEQ ? SEQ - 1 : tr);
        Pack8 p;
        p.u = *reinterpret_cast<const uint4*>(vg + baseBH + (size_t)tr * CH + seg * 8);
        #pragma unroll
        for (int e = 0; e < 8; e++) vt[seg * 8 + e][j] = p.h[e];
    }
    __syncthreads();

    const int wid = tid >> 6, lane = tid & 63, quad = lane >> 4, l16 = lane & 15;

    f32x4 sc[12];
    #pragma unroll
    for (int j = 0; j < 12; j++) sc[j] = zero4();
    #pragma unroll
    for (int kk = 0; kk < 2; kk++) {
        bf16x8 aq = *reinterpret_cast<const bf16x8*>(&qs[wid * 16 + l16][kk * 32 + quad * 8]);
        #pragma unroll
        for (int j = 0; j < 12; j++) {
            bf16x8 bk = *reinterpret_cast<const bf16x8*>(&ks[j * 16 + l16][kk * 32 + quad * 8]);
            sc[j] = __builtin_amdgcn_mfma_f32_16x16x32_bf16(aq, bk, sc[j], 0, 0, 0);
        }
    }
    __syncthreads();

    #pragma unroll
    for (int r = 0; r < 4; r++) {
        float s[12];
        float mx = -3.0e38f;
        #pragma unroll
        for (int j = 0; j < 12; j++) {
            int col = j * 16 + l16;
            int tr = kst + col;
            bool valid = (tr >= 0) && (tr < SEQ);
            s[j] = valid ? sc[j][r] : -3.0e38f;
            mx = fmaxf(mx, s[j]);
        }
        #pragma unroll
        for (int o = 1; o < 16; o <<= 1) mx = fmaxf(mx, __shfl_xor(mx, o, 64));
        float sum = 0.f;
        #pragma unroll
        for (int j = 0; j < 12; j++) {
            float e = __expf(s[j] - mx);
            s[j] = e;
            sum += e;
        }
        #pragma unroll
        for (int o = 1; o < 16; o <<= 1) sum += __shfl_xor(sum, o, 64);
        const float inv = 1.f / sum;
        const int row = wid * 16 + quad * 4 + r;
        #pragma unroll
        for (int j = 0; j < 12; j++)
            ps[row][j * 16 + l16] = __float2bfloat16(s[j] * inv);
    }
    __syncthreads();

    f32x4 oa[4];
    #pragma unroll
    for (int j = 0; j < 4; j++) oa[j] = zero4();
    #pragma unroll
    for (int kk = 0; kk < 6; kk++) {
        bf16x8 ap = *reinterpret_cast<const bf16x8*>(&ps[wid * 16 + l16][kk * 32 + quad * 8]);
        #pragma unroll
        for (int j = 0; j < 4; j++) {
            bf16x8 bv = *reinterpret_cast<const bf16x8*>(&vt[j * 16 + l16][kk * 32 + quad * 8]);
            oa[j] = __builtin_amdgcn_mfma_f32_16x16x32_bf16(ap, bv, oa[j], 0, 0, 0);
        }
    }
    #pragma unroll
    for (int j = 0; j < 4; j++) {
        const int d = j * 16 + l16;
        #pragma unroll
        for (int r = 0; r < 4; r++) {
            const int i = wid * 16 + quad * 4 + r;
            ctx[baseBH + (size_t)(t0 + i) * CH + d] = __float2bfloat16(oa[j][r]);
        }
    }
}

extern "C" void kernel_launch(void* const* d_in, const int* in_sizes, int n_in,
                              void* d_out, int out_size, void* d_ws, size_t ws_size,
                              hipStream_t stream)
{
    const float* query = (const float*)d_in[0];
    const float* key_i = (const float*)d_in[1];
    const float* value = (const float*)d_in[2];
    const float* Wq = (const float*)d_in[3];
    const float* bq = (const float*)d_in[4];
    const float* Wk = (const float*)d_in[5];
    const float* bk = (const float*)d_in[6];
    const float* Wv = (const float*)d_in[7];
    const float* bv = (const float*)d_in[8];
    const float* Wo = (const float*)d_in[9];
    const float* bo = (const float*)d_in[10];
    float* out = (float*)d_out;

    const size_t NELEM = (size_t)MR * CH;   // 16,777,216
    const size_t WELEM = (size_t)CH * CH;   // 1,048,576

    // ws layout (104 MiB):
    //   S0: xv (phase 1-2) -> cb (phase 3-4)
    //   S1: qb   S2: kb
    //   S3: packed weights wq|wk|wv|wo (2 MiB each)
    __hip_bfloat16* S0 = (__hip_bfloat16*)d_ws;
    __hip_bfloat16* S1 = S0 + NELEM;
    __hip_bfloat16* S2 = S1 + NELEM;
    __hip_bfloat16* S3 = S2 + NELEM;
    __hip_bfloat16* wqb = S3;
    __hip_bfloat16* wkb = S3 + WELEM;
    __hip_bfloat16* wvb = S3 + 2 * WELEM;
    __hip_bfloat16* wob = S3 + 3 * WELEM;

    // d_out doubles as scratch: xq|xk (bf16) until consumed, then vb.
    __hip_bfloat16* xq = (__hip_bfloat16*)d_out;
    __hip_bfloat16* xk = xq + NELEM;
    __hip_bfloat16* vb = (__hip_bfloat16*)d_out;   // after QK-GEMM consumed xq/xk
    __hip_bfloat16* qb = S1;
    __hip_bfloat16* kb = S2;
    __hip_bfloat16* cb = S0;

    const int nA8 = (int)(NELEM / 8);
    const int nW8 = (int)(WELEM / 8);

    pack_bf16<<<nA8 / 256, 256, 0, stream>>>(query, xq, nA8);
    pack_bf16<<<nA8 / 256, 256, 0, stream>>>(key_i, xk, nA8);
    pack_bf16<<<nA8 / 256, 256, 0, stream>>>(value, S0, nA8);
    pack_bf16<<<nW8 / 256, 256, 0, stream>>>(Wq, wqb, nW8);
    pack_bf16<<<nW8 / 256, 256, 0, stream>>>(Wk, wkb, nW8);
    pack_bf16<<<nW8 / 256, 256, 0, stream>>>(Wv, wvb, nW8);
    pack_bf16<<<nW8 / 256, 256, 0, stream>>>(Wo, wob, nW8);

    dim3 ggrid(CH / 128, MR / 128);         // (8, 128)
    dim3 qkgrid(CH / 128, MR / 128, 2);     // 2048 blocks

    gemm_qk<<<qkgrid, 256, 0, stream>>>(xq, wqb, bq, qb, 0.125f,
                                        xk, wkb, bk, kb);
    gemm_one<__hip_bfloat16><<<ggrid, 256, 0, stream>>>(S0, wvb, bv, vb);

    attn_kernel<<<BATCH * NH * NBL, 256, 0, stream>>>(qb, kb, vb, cb);

    gemm_one<float><<<ggrid, 256, 0, stream>>>(cb, wob, bo, out);
}

// Round 2
// 451.794 us; speedup vs baseline: 1.1111x; 1.0801x over previous
//
#include <hip/hip_runtime.h>
#include <hip/hip_bf16.h>
#include <type_traits>

#define BATCH 2
#define SEQ   8192
#define CH    1024
#define NH    16
#define BLK   64
#define WIN   192
#define NBL   128
#define DH    64
#define MR    (BATCH*SEQ)   // 16384

typedef __bf16 bf16x8 __attribute__((ext_vector_type(8)));
typedef float  f32x4  __attribute__((ext_vector_type(4)));

__device__ __forceinline__ f32x4 zero4() {
    f32x4 z; z[0]=0.f; z[1]=0.f; z[2]=0.f; z[3]=0.f; return z;
}

union Pack8 { __hip_bfloat16 h[8]; uint4 u; };

typedef const __attribute__((address_space(1))) unsigned int* gas_ptr;
typedef       __attribute__((address_space(3))) unsigned int* las_ptr;

__device__ __forceinline__ void gload_lds16(const __hip_bfloat16* g, __hip_bfloat16* l) {
    __builtin_amdgcn_global_load_lds((gas_ptr)(const void*)g, (las_ptr)(void*)l, 16, 0, 0);
}

__device__ __forceinline__ int xcd_swz(int bid, int nwg) {
    return (bid & 7) * (nwg >> 3) + (bid >> 3);
}

// ---- fp32 -> bf16 pack, 8 elements/thread
__global__ __launch_bounds__(256) void pack_bf16(
    const float* __restrict__ src, __hip_bfloat16* __restrict__ dst, int n8)
{
    int i = blockIdx.x * 256 + threadIdx.x;
    if (i >= n8) return;
    const float4* s = reinterpret_cast<const float4*>(src);
    float4 a = s[2 * i], b = s[2 * i + 1];
    Pack8 p;
    p.h[0] = __float2bfloat16(a.x); p.h[1] = __float2bfloat16(a.y);
    p.h[2] = __float2bfloat16(a.z); p.h[3] = __float2bfloat16(a.w);
    p.h[4] = __float2bfloat16(b.x); p.h[5] = __float2bfloat16(b.y);
    p.h[6] = __float2bfloat16(b.z); p.h[7] = __float2bfloat16(b.w);
    reinterpret_cast<uint4*>(dst)[i] = p.u;
}

// =====================================================================
// 256x256 GEMM, BK=64, 8 waves (2M x 4N), 4-phase counted-vmcnt pipeline
// (T2+T3+T4+T5).  C[M,N] = alpha*(A @ Wb^T + bias), K = N = CH.
//
// LDS (128 KiB, double-buffered):
//   A: [buf][khalf][1024 chunks of 16B]   elems [0, 32768)
//   B: same, elems [32768, 65536)
// Chunk c of a 256x32 k-half holds row r=c>>2, col-quad s=(c&3)^(r&3)
// (2-bit XOR swizzle -> b128 frag reads land 8 lanes/bank-group = floor).
//
// Per K-tile, 4 phases: (mh0,klo)(mh1,klo)(mh0,khi)(mh1,khi).  Each phase
// stages ONE k-half of tile t+1 (order A-klo,B-klo,A-khi,B-khi) so that
// vmcnt(4) at phases 0/2 guarantees exactly the halves about to be read
// have landed while 4 loads stay in flight (never drain in main loop).
// Stage target buffer's previous tile finished >=1 barrier earlier -> no
// overwrite race.
// =====================================================================

__device__ __forceinline__ void stage_half(
    const __hip_bfloat16* __restrict__ g, int goff,
    __hip_bfloat16* sm, int loff, int tid)
{
    gload_lds16(g + goff,            sm + loff + tid * 8);
    gload_lds16(g + goff + 128 * CH, sm + loff + (tid + 512) * 8);
}

template<int MH, int KS>
__device__ __forceinline__ void phase_mfma(
    const __hip_bfloat16* As_, const __hip_bfloat16* Bs_,
    int aoff, int boff, f32x4 (&acc)[8][4])
{
    bf16x8 af[4], bf[4];
    #pragma unroll
    for (int i = 0; i < 4; ++i)
        af[i] = *reinterpret_cast<const bf16x8*>(As_ + KS * 8192 + (MH * 4 + i) * 512 + aoff);
    #pragma unroll
    for (int j = 0; j < 4; ++j)
        bf[j] = *reinterpret_cast<const bf16x8*>(Bs_ + KS * 8192 + j * 512 + boff);
    asm volatile("s_waitcnt lgkmcnt(0)" ::: "memory");
    __builtin_amdgcn_sched_barrier(0);
    __builtin_amdgcn_s_setprio(1);
    #pragma unroll
    for (int i = 0; i < 4; ++i)
        #pragma unroll
        for (int j = 0; j < 4; ++j)
            acc[MH * 4 + i][j] = __builtin_amdgcn_mfma_f32_16x16x32_bf16(
                af[i], bf[j], acc[MH * 4 + i][j], 0, 0, 0);
    __builtin_amdgcn_s_setprio(0);
}

template<typename OT>
__device__ __forceinline__ void gemm_body256(
    const __hip_bfloat16* __restrict__ A, const __hip_bfloat16* __restrict__ Wb,
    const float* __restrict__ bias, OT* __restrict__ out, float alpha,
    int m0, int n0, __hip_bfloat16* sm)
{
    const int tid  = threadIdx.x;
    const int wid  = tid >> 6;
    const int lane = tid & 63;
    const int quad = lane >> 4;
    const int l16  = lane & 15;
    const int wr   = wid >> 2, wc = wid & 3;   // 2 x 4 wave grid, 128x64 out each

    // staging: chunk c=tid covers rows 0..127, c=tid+512 rows 128..255 (same seg)
    const int r0 = tid >> 2;
    const int s0 = (tid & 3) ^ (r0 & 3);
    const int offA0 = (m0 + r0) * CH + s0 * 8;
    const int offB0 = (n0 + r0) * CH + s0 * 8;

    // frag-read element offsets (row r, quad) -> chunk r*4 + (quad^(r&3))
    const int cq   = quad ^ (l16 & 3);
    const int aoff = ((wr * 128 + l16) * 4 + cq) * 8;
    const int boff = ((wc * 64  + l16) * 4 + cq) * 8;

    f32x4 acc[8][4];
    #pragma unroll
    for (int i = 0; i < 8; ++i)
        #pragma unroll
        for (int j = 0; j < 4; ++j) acc[i][j] = zero4();

    // ---- prologue: tile 0 -> buf 0, issue order A-klo, B-klo, A-khi, B-khi
    stage_half(A,  offA0,      sm, 0,             tid);
    stage_half(Wb, offB0,      sm, 32768,         tid);
    stage_half(A,  offA0 + 32, sm, 8192,          tid);
    stage_half(Wb, offB0 + 32, sm, 32768 + 8192,  tid);

    #pragma unroll 1
    for (int t = 0; t < 15; ++t) {
        const int cur = t & 1, nb = cur ^ 1;
        const int kn  = (t + 1) * 64;
        const __hip_bfloat16* As_ = sm + cur * 16384;
        const __hip_bfloat16* Bs_ = sm + 32768 + cur * 16384;

        // phase 0: compute (mh0, klo); stage A-klo(t+1)
        asm volatile("s_waitcnt vmcnt(4)" ::: "memory");
        __builtin_amdgcn_s_barrier();
        __builtin_amdgcn_sched_barrier(0);
        stage_half(A, offA0 + kn, sm, nb * 16384, tid);
        phase_mfma<0, 0>(As_, Bs_, aoff, boff, acc);

        // phase 1: (mh1, klo); stage B-klo(t+1)
        __builtin_amdgcn_s_barrier();
        __builtin_amdgcn_sched_barrier(0);
        stage_half(Wb, offB0 + kn, sm, 32768 + nb * 16384, tid);
        phase_mfma<1, 0>(As_, Bs_, aoff, boff, acc);

        // phase 2: (mh0, khi); stage A-khi(t+1)
        asm volatile("s_waitcnt vmcnt(4)" ::: "memory");
        __builtin_amdgcn_s_barrier();
        __builtin_amdgcn_sched_barrier(0);
        stage_half(A, offA0 + kn + 32, sm, nb * 16384 + 8192, tid);
        phase_mfma<0, 1>(As_, Bs_, aoff, boff, acc);

        // phase 3: (mh1, khi); stage B-khi(t+1)
        __builtin_amdgcn_s_barrier();
        __builtin_amdgcn_sched_barrier(0);
        stage_half(Wb, offB0 + kn + 32, sm, 32768 + nb * 16384 + 8192, tid);
        phase_mfma<1, 1>(As_, Bs_, aoff, boff, acc);
    }

    // ---- peeled last tile (t=15, cur=1): no staging; drain khi at phase 2
    {
        const __hip_bfloat16* As_ = sm + 16384;
        const __hip_bfloat16* Bs_ = sm + 32768 + 16384;

        asm volatile("s_waitcnt vmcnt(4)" ::: "memory");
        __builtin_amdgcn_s_barrier();
        __builtin_amdgcn_sched_barrier(0);
        phase_mfma<0, 0>(As_, Bs_, aoff, boff, acc);

        __builtin_amdgcn_s_barrier();
        __builtin_amdgcn_sched_barrier(0);
        phase_mfma<1, 0>(As_, Bs_, aoff, boff, acc);

        asm volatile("s_waitcnt vmcnt(0)" ::: "memory");
        __builtin_amdgcn_s_barrier();
        __builtin_amdgcn_sched_barrier(0);
        phase_mfma<0, 1>(As_, Bs_, aoff, boff, acc);

        __builtin_amdgcn_s_barrier();
        __builtin_amdgcn_sched_barrier(0);
        phase_mfma<1, 1>(As_, Bs_, aoff, boff, acc);
    }

    // ---- epilogue
    #pragma unroll
    for (int j = 0; j < 4; ++j) {
        const int col = n0 + wc * 64 + j * 16 + l16;
        const float bv = bias[col];
        #pragma unroll
        for (int i = 0; i < 8; ++i) {
            #pragma unroll
            for (int r = 0; r < 4; ++r) {
                const int row = m0 + wr * 128 + i * 16 + quad * 4 + r;
                float v = alpha * (acc[i][j][r] + bv);
                if constexpr (std::is_same<OT, float>::value)
                    out[(size_t)row * CH + col] = v;
                else
                    out[(size_t)row * CH + col] = __float2bfloat16(v);
            }
        }
    }
}

// Grid per GEMM: (4, 64) = 256 blocks (1/CU).  XCD chunk = 8 M-panels x 4
// N-tiles -> per-XCD footprint/k-step ~384 KB << 4 MiB L2.
__device__ __forceinline__ void gemm_tile256(int& m0, int& n0) {
    int bid = blockIdx.y * 4 + blockIdx.x;       // [0,256)
    int swz = (bid & 7) * 32 + (bid >> 3);
    m0 = (swz >> 2) * 256;
    n0 = (swz & 3) * 256;
}

__global__ __launch_bounds__(512, 2) void gemm_qk256(
    const __hip_bfloat16* __restrict__ A0, const __hip_bfloat16* __restrict__ W0,
    const float* __restrict__ b0, __hip_bfloat16* __restrict__ o0, float alpha0,
    const __hip_bfloat16* __restrict__ A1, const __hip_bfloat16* __restrict__ W1,
    const float* __restrict__ b1, __hip_bfloat16* __restrict__ o1)
{
    __shared__ alignas(16) __hip_bfloat16 sm[65536];   // 128 KiB
    int m0, n0; gemm_tile256(m0, n0);
    if (blockIdx.z == 0)
        gemm_body256<__hip_bfloat16>(A0, W0, b0, o0, alpha0, m0, n0, sm);
    else
        gemm_body256<__hip_bfloat16>(A1, W1, b1, o1, 1.0f, m0, n0, sm);
}

template<typename OT>
__global__ __launch_bounds__(512, 2) void gemm_one256(
    const __hip_bfloat16* __restrict__ A, const __hip_bfloat16* __restrict__ Wb,
    const float* __restrict__ bias, OT* __restrict__ out)
{
    __shared__ alignas(16) __hip_bfloat16 sm[65536];   // 128 KiB
    int m0, n0; gemm_tile256(m0, n0);
    gemm_body256<OT>(A, Wb, bias, out, 1.0f, m0, n0, sm);
}

// One workgroup per (b, h, block-of-64-queries). Window of 192 keys
// starting at t0-64 (clamped loads, analytic masking).
__global__ __launch_bounds__(256) void attn_kernel(
    const __hip_bfloat16* __restrict__ qg,
    const __hip_bfloat16* __restrict__ kg,
    const __hip_bfloat16* __restrict__ vg,
    __hip_bfloat16* __restrict__ ctx)
{
    __shared__ alignas(16) char smem[62464];
    auto qs = reinterpret_cast<__hip_bfloat16(*)[72]>(smem);
    auto ks = reinterpret_cast<__hip_bfloat16(*)[72]>(smem + 9216);
    auto vt = reinterpret_cast<__hip_bfloat16(*)[200]>(smem + 36864);
    auto ps = reinterpret_cast<__hip_bfloat16(*)[200]>(smem);

    const int blk = xcd_swz(blockIdx.x, BATCH * NH * NBL);
    const int n = blk & (NBL - 1);
    const int h = (blk >> 7) & (NH - 1);
    const int b = blk >> 11;
    const int t0  = n * BLK;
    const int kst = t0 - 64;
    const int tid = threadIdx.x;
    const size_t baseBH = (size_t)b * SEQ * CH + (size_t)h * DH;

    #pragma unroll
    for (int it = 0; it < 2; it++) {
        int c = tid + it * 256;
        int row = c >> 3, seg = c & 7;
        *reinterpret_cast<uint4*>(&qs[row][seg * 8]) =
            *reinterpret_cast<const uint4*>(qg + baseBH + (size_t)(t0 + row) * CH + seg * 8);
    }
    #pragma unroll
    for (int it = 0; it < 6; it++) {
        int c = tid + it * 256;
        int row = c >> 3, seg = c & 7;
        int tr = kst + row; tr = tr < 0 ? 0 : (tr >= SEQ ? SEQ - 1 : tr);
        *reinterpret_cast<uint4*>(&ks[row][seg * 8]) =
            *reinterpret_cast<const uint4*>(kg + baseBH + (size_t)tr * CH + seg * 8);
    }
    #pragma unroll
    for (int it = 0; it < 6; it++) {
        int c = tid + it * 256;
        int j = c % WIN, seg = c / WIN;
        int tr = kst + j; tr = tr < 0 ? 0 : (tr >= SEQ ? SEQ - 1 : tr);
        Pack8 p;
        p.u = *reinterpret_cast<const uint4*>(vg + baseBH + (size_t)tr * CH + seg * 8);
        #pragma unroll
        for (int e = 0; e < 8; e++) vt[seg * 8 + e][j] = p.h[e];
    }
    __syncthreads();

    const int wid = tid >> 6, lane = tid & 63, quad = lane >> 4, l16 = lane & 15;

    f32x4 sc[12];
    #pragma unroll
    for (int j = 0; j < 12; j++) sc[j] = zero4();
    #pragma unroll
    for (int kk = 0; kk < 2; kk++) {
        bf16x8 aq = *reinterpret_cast<const bf16x8*>(&qs[wid * 16 + l16][kk * 32 + quad * 8]);
        #pragma unroll
        for (int j = 0; j < 12; j++) {
            bf16x8 bk = *reinterpret_cast<const bf16x8*>(&ks[j * 16 + l16][kk * 32 + quad * 8]);
            sc[j] = __builtin_amdgcn_mfma_f32_16x16x32_bf16(aq, bk, sc[j], 0, 0, 0);
        }
    }
    __syncthreads();

    #pragma unroll
    for (int r = 0; r < 4; r++) {
        float s[12];
        float mx = -3.0e38f;
        #pragma unroll
        for (int j = 0; j < 12; j++) {
            int col = j * 16 + l16;
            int tr = kst + col;
            bool valid = (tr >= 0) && (tr < SEQ);
            s[j] = valid ? sc[j][r] : -3.0e38f;
            mx = fmaxf(mx, s[j]);
        }
        #pragma unroll
        for (int o = 1; o < 16; o <<= 1) mx = fmaxf(mx, __shfl_xor(mx, o, 64));
        float sum = 0.f;
        #pragma unroll
        for (int j = 0; j < 12; j++) {
            float e = __expf(s[j] - mx);
            s[j] = e;
            sum += e;
        }
        #pragma unroll
        for (int o = 1; o < 16; o <<= 1) sum += __shfl_xor(sum, o, 64);
        const float inv = 1.f / sum;
        const int row = wid * 16 + quad * 4 + r;
        #pragma unroll
        for (int j = 0; j < 12; j++)
            ps[row][j * 16 + l16] = __float2bfloat16(s[j] * inv);
    }
    __syncthreads();

    f32x4 oa[4];
    #pragma unroll
    for (int j = 0; j < 4; j++) oa[j] = zero4();
    #pragma unroll
    for (int kk = 0; kk < 6; kk++) {
        bf16x8 ap = *reinterpret_cast<const bf16x8*>(&ps[wid * 16 + l16][kk * 32 + quad * 8]);
        #pragma unroll
        for (int j = 0; j < 4; j++) {
            bf16x8 bv = *reinterpret_cast<const bf16x8*>(&vt[j * 16 + l16][kk * 32 + quad * 8]);
            oa[j] = __builtin_amdgcn_mfma_f32_16x16x32_bf16(ap, bv, oa[j], 0, 0, 0);
        }
    }
    #pragma unroll
    for (int j = 0; j < 4; j++) {
        const int d = j * 16 + l16;
        #pragma unroll
        for (int r = 0; r < 4; r++) {
            const int i = wid * 16 + quad * 4 + r;
            ctx[baseBH + (size_t)(t0 + i) * CH + d] = __float2bfloat16(oa[j][r]);
        }
    }
}

extern "C" void kernel_launch(void* const* d_in, const int* in_sizes, int n_in,
                              void* d_out, int out_size, void* d_ws, size_t ws_size,
                              hipStream_t stream)
{
    const float* query = (const float*)d_in[0];
    const float* key_i = (const float*)d_in[1];
    const float* value = (const float*)d_in[2];
    const float* Wq = (const float*)d_in[3];
    const float* bq = (const float*)d_in[4];
    const float* Wk = (const float*)d_in[5];
    const float* bk = (const float*)d_in[6];
    const float* Wv = (const float*)d_in[7];
    const float* bv = (const float*)d_in[8];
    const float* Wo = (const float*)d_in[9];
    const float* bo = (const float*)d_in[10];
    float* out = (float*)d_out;

    const size_t NELEM = (size_t)MR * CH;   // 16,777,216
    const size_t WELEM = (size_t)CH * CH;   // 1,048,576

    __hip_bfloat16* S0 = (__hip_bfloat16*)d_ws;
    __hip_bfloat16* S1 = S0 + NELEM;
    __hip_bfloat16* S2 = S1 + NELEM;
    __hip_bfloat16* S3 = S2 + NELEM;
    __hip_bfloat16* wqb = S3;
    __hip_bfloat16* wkb = S3 + WELEM;
    __hip_bfloat16* wvb = S3 + 2 * WELEM;
    __hip_bfloat16* wob = S3 + 3 * WELEM;

    __hip_bfloat16* xq = (__hip_bfloat16*)d_out;
    __hip_bfloat16* xk = xq + NELEM;
    __hip_bfloat16* vb = (__hip_bfloat16*)d_out;
    __hip_bfloat16* qb = S1;
    __hip_bfloat16* kb = S2;
    __hip_bfloat16* cb = S0;

    const int nA8 = (int)(NELEM / 8);
    const int nW8 = (int)(WELEM / 8);

    pack_bf16<<<nA8 / 256, 256, 0, stream>>>(query, xq, nA8);
    pack_bf16<<<nA8 / 256, 256, 0, stream>>>(key_i, xk, nA8);
    pack_bf16<<<nA8 / 256, 256, 0, stream>>>(value, S0, nA8);
    pack_bf16<<<nW8 / 256, 256, 0, stream>>>(Wq, wqb, nW8);
    pack_bf16<<<nW8 / 256, 256, 0, stream>>>(Wk, wkb, nW8);
    pack_bf16<<<nW8 / 256, 256, 0, stream>>>(Wv, wvb, nW8);
    pack_bf16<<<nW8 / 256, 256, 0, stream>>>(Wo, wob, nW8);

    dim3 ggrid(CH / 256, MR / 256);         // (4, 64)
    dim3 qkgrid(CH / 256, MR / 256, 2);     // 512 blocks

    gemm_qk256<<<qkgrid, 512, 0, stream>>>(xq, wqb, bq, qb, 0.125f,
                                           xk, wkb, bk, kb);
    gemm_one256<__hip_bfloat16><<<ggrid, 512, 0, stream>>>(S0, wvb, bv, vb);

    attn_kernel<<<BATCH * NH * NBL, 256, 0, stream>>>(qb, kb, vb, cb);

    gemm_one256<float><<<ggrid, 512, 0, stream>>>(cb, wob, bo, out);
}

// Round 3
// 447.581 us; speedup vs baseline: 1.1215x; 1.0094x over previous
//
#include <hip/hip_runtime.h>
#include <hip/hip_bf16.h>
#include <type_traits>

#define BATCH 2
#define SEQ   8192
#define CH    1024
#define NH    16
#define BLK   64
#define WIN   192
#define NBL   128
#define DH    64
#define MR    (BATCH*SEQ)   // 16384

typedef __bf16 bf16x8 __attribute__((ext_vector_type(8)));
typedef float  f32x4  __attribute__((ext_vector_type(4)));

__device__ __forceinline__ f32x4 zero4() {
    f32x4 z; z[0]=0.f; z[1]=0.f; z[2]=0.f; z[3]=0.f; return z;
}

union Pack8 { __hip_bfloat16 h[8]; uint4 u; };

typedef const __attribute__((address_space(1))) unsigned int* gas_ptr;
typedef       __attribute__((address_space(3))) unsigned int* las_ptr;

__device__ __forceinline__ void gload_lds16(const __hip_bfloat16* g, __hip_bfloat16* l) {
    __builtin_amdgcn_global_load_lds((gas_ptr)(const void*)g, (las_ptr)(void*)l, 16, 0, 0);
}

__device__ __forceinline__ int xcd_swz(int bid, int nwg) {
    return (bid & 7) * (nwg >> 3) + (bid >> 3);
}

// ---- fp32 -> bf16 pack, 8 elements/thread
__global__ __launch_bounds__(256) void pack_bf16(
    const float* __restrict__ src, __hip_bfloat16* __restrict__ dst, int n8)
{
    int i = blockIdx.x * 256 + threadIdx.x;
    if (i >= n8) return;
    const float4* s = reinterpret_cast<const float4*>(src);
    float4 a = s[2 * i], b = s[2 * i + 1];
    Pack8 p;
    p.h[0] = __float2bfloat16(a.x); p.h[1] = __float2bfloat16(a.y);
    p.h[2] = __float2bfloat16(a.z); p.h[3] = __float2bfloat16(a.w);
    p.h[4] = __float2bfloat16(b.x); p.h[5] = __float2bfloat16(b.y);
    p.h[6] = __float2bfloat16(b.z); p.h[7] = __float2bfloat16(b.w);
    reinterpret_cast<uint4*>(dst)[i] = p.u;
}

// =====================================================================
// 256x256 GEMM, BK=64, 8 waves (2M x 4N), 2-phase-per-tile counted-vmcnt
// pipeline.  C[M,N] = alpha*(A @ Wb^T + bias), K = N = CH.
//
// LDS (128 KiB, dbuf): A [buf][khalf][1024x16B] in [0,32768) elems,
// B same in [32768,65536).  Chunk c holds row r=c>>2, global col-quad
// s=(c&3)^((r>>1)&3).  Octet-bijective: chunk%8 = 4*(l16&1)+(quad^((l16>>1)&3))
// hits all 8 bank groups within every 8 consecutive lanes.
//
// Per tile, 2 phases (klo, khi).  Each phase: counted vmcnt(4) + barrier,
// stage one k-half of tile t+1, then 12 ds_read_b128 (bf0-3 once, af0-7)
// laddered with counted lgkmcnt(2) so reads stay ~3-deep in flight under
// the 32-MFMA cluster.  B-frags read ONCE per phase (shared across all 8
// row-frags) -> 24 reads/tile/wave (was 32).
// =====================================================================

__device__ __forceinline__ void stage_half(
    const __hip_bfloat16* __restrict__ g, int goff,
    __hip_bfloat16* sm, int loff, int tid)
{
    gload_lds16(g + goff,            sm + loff + tid * 8);
    gload_lds16(g + goff + 128 * CH, sm + loff + (tid + 512) * 8);
}

#define SB0 __builtin_amdgcn_sched_barrier(0)
#define LGKM(n) do { asm volatile("s_waitcnt lgkmcnt(" #n ")" ::: "memory"); \
                     __builtin_amdgcn_sched_barrier(0); } while (0)
#define MFMA4(i, areg) do { \
    acc[i][0] = __builtin_amdgcn_mfma_f32_16x16x32_bf16(areg, bf0, acc[i][0], 0, 0, 0); \
    acc[i][1] = __builtin_amdgcn_mfma_f32_16x16x32_bf16(areg, bf1, acc[i][1], 0, 0, 0); \
    acc[i][2] = __builtin_amdgcn_mfma_f32_16x16x32_bf16(areg, bf2, acc[i][2], 0, 0, 0); \
    acc[i][3] = __builtin_amdgcn_mfma_f32_16x16x32_bf16(areg, bf3, acc[i][3], 0, 0, 0); } while (0)

template<int KS>
__device__ __forceinline__ void phase_mfma2(
    const __hip_bfloat16* As_, const __hip_bfloat16* Bs_,
    int aoff, int boff, f32x4 (&acc)[8][4])
{
    const __hip_bfloat16* Ak = As_ + KS * 8192;
    const __hip_bfloat16* Bk = Bs_ + KS * 8192;
    bf16x8 bf0 = *reinterpret_cast<const bf16x8*>(Bk + boff);
    bf16x8 bf1 = *reinterpret_cast<const bf16x8*>(Bk + boff + 512);
    bf16x8 bf2 = *reinterpret_cast<const bf16x8*>(Bk + boff + 1024);
    bf16x8 bf3 = *reinterpret_cast<const bf16x8*>(Bk + boff + 1536);
    bf16x8 a0  = *reinterpret_cast<const bf16x8*>(Ak + aoff);
    bf16x8 a1  = *reinterpret_cast<const bf16x8*>(Ak + aoff + 512);
    bf16x8 a2  = *reinterpret_cast<const bf16x8*>(Ak + aoff + 1024);
    SB0;                                   // pinned: 7 reads in flight
    __builtin_amdgcn_s_setprio(1);
    LGKM(2);  MFMA4(0, a0);                // bf0-3 + a0 landed
    bf16x8 a3 = *reinterpret_cast<const bf16x8*>(Ak + aoff + 3 * 512); SB0;
    LGKM(2);  MFMA4(1, a1);
    a0 = *reinterpret_cast<const bf16x8*>(Ak + aoff + 4 * 512); SB0;
    LGKM(2);  MFMA4(2, a2);
    a1 = *reinterpret_cast<const bf16x8*>(Ak + aoff + 5 * 512); SB0;
    LGKM(2);  MFMA4(3, a3);
    a2 = *reinterpret_cast<const bf16x8*>(Ak + aoff + 6 * 512); SB0;
    LGKM(2);  MFMA4(4, a0);
    a3 = *reinterpret_cast<const bf16x8*>(Ak + aoff + 7 * 512); SB0;
    LGKM(2);  MFMA4(5, a1);
    LGKM(1);  MFMA4(6, a2);
    LGKM(0);  MFMA4(7, a3);
    __builtin_amdgcn_s_setprio(0);
}

template<typename OT>
__device__ __forceinline__ void gemm_body256(
    const __hip_bfloat16* __restrict__ A, const __hip_bfloat16* __restrict__ Wb,
    const float* __restrict__ bias, OT* __restrict__ out, float alpha,
    int m0, int n0, __hip_bfloat16* sm)
{
    const int tid  = threadIdx.x;
    const int wid  = tid >> 6;
    const int lane = tid & 63;
    const int quad = lane >> 4;
    const int l16  = lane & 15;
    const int wr   = wid >> 2, wc = wid & 3;   // 2 x 4 wave grid, 128x64 out each

    // staging: chunk c=tid -> row tid>>2, global seg (tid&3)^((tid>>3)&3);
    // chunk tid+512 -> row +128, same seg (128>>1 ≡ 0 mod 4).
    const int r0 = tid >> 2;
    const int s0 = (tid & 3) ^ ((tid >> 3) & 3);
    const int offA0 = (m0 + r0) * CH + s0 * 8;
    const int offB0 = (n0 + r0) * CH + s0 * 8;

    // frag reads: row r -> chunk r*4 + (quad^((r>>1)&3)); r&2-bit == l16's
    const int cq   = quad ^ ((l16 >> 1) & 3);
    const int aoff = ((wr * 128 + l16) * 4 + cq) * 8;
    const int boff = ((wc * 64  + l16) * 4 + cq) * 8;

    f32x4 acc[8][4];
    #pragma unroll
    for (int i = 0; i < 8; ++i)
        #pragma unroll
        for (int j = 0; j < 4; ++j) acc[i][j] = zero4();

    // ---- prologue: tile 0 -> buf 0, order A-klo, B-klo, A-khi, B-khi (8 insts)
    stage_half(A,  offA0,      sm, 0,             tid);
    stage_half(Wb, offB0,      sm, 32768,         tid);
    stage_half(A,  offA0 + 32, sm, 8192,          tid);
    stage_half(Wb, offB0 + 32, sm, 32768 + 8192,  tid);

    #pragma unroll 1
    for (int t = 0; t < 15; ++t) {
        const int cur = t & 1, nb = cur ^ 1;
        const int kn  = (t + 1) * 64;
        const __hip_bfloat16* As_ = sm + cur * 16384;
        const __hip_bfloat16* Bs_ = sm + 32768 + cur * 16384;

        // phase 0 (klo): oldest 4 of 8 in flight = klo(t)
        asm volatile("s_waitcnt vmcnt(4)" ::: "memory");
        __builtin_amdgcn_s_barrier();
        SB0;
        stage_half(A,  offA0 + kn, sm, nb * 16384, tid);
        stage_half(Wb, offB0 + kn, sm, 32768 + nb * 16384, tid);
        phase_mfma2<0>(As_, Bs_, aoff, boff, acc);

        // phase 1 (khi): oldest 4 of 8 = khi(t)
        asm volatile("s_waitcnt vmcnt(4)" ::: "memory");
        __builtin_amdgcn_s_barrier();
        SB0;
        stage_half(A,  offA0 + kn + 32, sm, nb * 16384 + 8192, tid);
        stage_half(Wb, offB0 + kn + 32, sm, 32768 + nb * 16384 + 8192, tid);
        phase_mfma2<1>(As_, Bs_, aoff, boff, acc);
    }

    // ---- peeled last tile (t=15, cur=1): no staging
    {
        const __hip_bfloat16* As_ = sm + 16384;
        const __hip_bfloat16* Bs_ = sm + 32768 + 16384;

        asm volatile("s_waitcnt vmcnt(4)" ::: "memory");
        __builtin_amdgcn_s_barrier();
        SB0;
        phase_mfma2<0>(As_, Bs_, aoff, boff, acc);

        asm volatile("s_waitcnt vmcnt(0)" ::: "memory");
        __builtin_amdgcn_s_barrier();
        SB0;
        phase_mfma2<1>(As_, Bs_, aoff, boff, acc);
    }

    // ---- epilogue
    #pragma unroll
    for (int j = 0; j < 4; ++j) {
        const int col = n0 + wc * 64 + j * 16 + l16;
        const float bv = bias[col];
        #pragma unroll
        for (int i = 0; i < 8; ++i) {
            #pragma unroll
            for (int r = 0; r < 4; ++r) {
                const int row = m0 + wr * 128 + i * 16 + quad * 4 + r;
                float v = alpha * (acc[i][j][r] + bv);
                if constexpr (std::is_same<OT, float>::value)
                    out[(size_t)row * CH + col] = v;
                else
                    out[(size_t)row * CH + col] = __float2bfloat16(v);
            }
        }
    }
}

// Grid per GEMM: (4, 64) = 256 blocks (1/CU).  XCD chunk = 8 M-panels x 4
// N-tiles -> per-XCD footprint/k-step ~384 KB << 4 MiB L2.
__device__ __forceinline__ void gemm_tile256(int& m0, int& n0) {
    int bid = blockIdx.y * 4 + blockIdx.x;       // [0,256)
    int swz = (bid & 7) * 32 + (bid >> 3);
    m0 = (swz >> 2) * 256;
    n0 = (swz & 3) * 256;
}

__global__ __launch_bounds__(512, 2) void gemm_qk256(
    const __hip_bfloat16* __restrict__ A0, const __hip_bfloat16* __restrict__ W0,
    const float* __restrict__ b0, __hip_bfloat16* __restrict__ o0, float alpha0,
    const __hip_bfloat16* __restrict__ A1, const __hip_bfloat16* __restrict__ W1,
    const float* __restrict__ b1, __hip_bfloat16* __restrict__ o1)
{
    __shared__ alignas(16) __hip_bfloat16 sm[65536];   // 128 KiB
    int m0, n0; gemm_tile256(m0, n0);
    if (blockIdx.z == 0)
        gemm_body256<__hip_bfloat16>(A0, W0, b0, o0, alpha0, m0, n0, sm);
    else
        gemm_body256<__hip_bfloat16>(A1, W1, b1, o1, 1.0f, m0, n0, sm);
}

template<typename OT>
__global__ __launch_bounds__(512, 2) void gemm_one256(
    const __hip_bfloat16* __restrict__ A, const __hip_bfloat16* __restrict__ Wb,
    const float* __restrict__ bias, OT* __restrict__ out)
{
    __shared__ alignas(16) __hip_bfloat16 sm[65536];   // 128 KiB
    int m0, n0; gemm_tile256(m0, n0);
    gemm_body256<OT>(A, Wb, bias, out, 1.0f, m0, n0, sm);
}

// One workgroup per (b, h, block-of-64-queries). Window of 192 keys
// starting at t0-64 (clamped loads, analytic masking).
__global__ __launch_bounds__(256) void attn_kernel(
    const __hip_bfloat16* __restrict__ qg,
    const __hip_bfloat16* __restrict__ kg,
    const __hip_bfloat16* __restrict__ vg,
    __hip_bfloat16* __restrict__ ctx)
{
    __shared__ alignas(16) char smem[62464];
    auto qs = reinterpret_cast<__hip_bfloat16(*)[72]>(smem);
    auto ks = reinterpret_cast<__hip_bfloat16(*)[72]>(smem + 9216);
    auto vt = reinterpret_cast<__hip_bfloat16(*)[200]>(smem + 36864);
    auto ps = reinterpret_cast<__hip_bfloat16(*)[200]>(smem);

    const int blk = xcd_swz(blockIdx.x, BATCH * NH * NBL);
    const int n = blk & (NBL - 1);
    const int h = (blk >> 7) & (NH - 1);
    const int b = blk >> 11;
    const int t0  = n * BLK;
    const int kst = t0 - 64;
    const int tid = threadIdx.x;
    const size_t baseBH = (size_t)b * SEQ * CH + (size_t)h * DH;

    #pragma unroll
    for (int it = 0; it < 2; it++) {
        int c = tid + it * 256;
        int row = c >> 3, seg = c & 7;
        *reinterpret_cast<uint4*>(&qs[row][seg * 8]) =
            *reinterpret_cast<const uint4*>(qg + baseBH + (size_t)(t0 + row) * CH + seg * 8);
    }
    #pragma unroll
    for (int it = 0; it < 6; it++) {
        int c = tid + it * 256;
        int row = c >> 3, seg = c & 7;
        int tr = kst + row; tr = tr < 0 ? 0 : (tr >= SEQ ? SEQ - 1 : tr);
        *reinterpret_cast<uint4*>(&ks[row][seg * 8]) =
            *reinterpret_cast<const uint4*>(kg + baseBH + (size_t)tr * CH + seg * 8);
    }
    #pragma unroll
    for (int it = 0; it < 6; it++) {
        int c = tid + it * 256;
        int j = c % WIN, seg = c / WIN;
        int tr = kst + j; tr = tr < 0 ? 0 : (tr >= SEQ ? SEQ - 1 : tr);
        Pack8 p;
        p.u = *reinterpret_cast<const uint4*>(vg + baseBH + (size_t)tr * CH + seg * 8);
        #pragma unroll
        for (int e = 0; e < 8; e++) vt[seg * 8 + e][j] = p.h[e];
    }
    __syncthreads();

    const int wid = tid >> 6, lane = tid & 63, quad = lane >> 4, l16 = lane & 15;

    f32x4 sc[12];
    #pragma unroll
    for (int j = 0; j < 12; j++) sc[j] = zero4();
    #pragma unroll
    for (int kk = 0; kk < 2; kk++) {
        bf16x8 aq = *reinterpret_cast<const bf16x8*>(&qs[wid * 16 + l16][kk * 32 + quad * 8]);
        #pragma unroll
        for (int j = 0; j < 12; j++) {
            bf16x8 bk = *reinterpret_cast<const bf16x8*>(&ks[j * 16 + l16][kk * 32 + quad * 8]);
            sc[j] = __builtin_amdgcn_mfma_f32_16x16x32_bf16(aq, bk, sc[j], 0, 0, 0);
        }
    }
    __syncthreads();

    #pragma unroll
    for (int r = 0; r < 4; r++) {
        float s[12];
        float mx = -3.0e38f;
        #pragma unroll
        for (int j = 0; j < 12; j++) {
            int col = j * 16 + l16;
            int tr = kst + col;
            bool valid = (tr >= 0) && (tr < SEQ);
            s[j] = valid ? sc[j][r] : -3.0e38f;
            mx = fmaxf(mx, s[j]);
        }
        #pragma unroll
        for (int o = 1; o < 16; o <<= 1) mx = fmaxf(mx, __shfl_xor(mx, o, 64));
        float sum = 0.f;
        #pragma unroll
        for (int j = 0; j < 12; j++) {
            float e = __expf(s[j] - mx);
            s[j] = e;
            sum += e;
        }
        #pragma unroll
        for (int o = 1; o < 16; o <<= 1) sum += __shfl_xor(sum, o, 64);
        const float inv = 1.f / sum;
        const int row = wid * 16 + quad * 4 + r;
        #pragma unroll
        for (int j = 0; j < 12; j++)
            ps[row][j * 16 + l16] = __float2bfloat16(s[j] * inv);
    }
    __syncthreads();

    f32x4 oa[4];
    #pragma unroll
    for (int j = 0; j < 4; j++) oa[j] = zero4();
    #pragma unroll
    for (int kk = 0; kk < 6; kk++) {
        bf16x8 ap = *reinterpret_cast<const bf16x8*>(&ps[wid * 16 + l16][kk * 32 + quad * 8]);
        #pragma unroll
        for (int j = 0; j < 4; j++) {
            bf16x8 bv = *reinterpret_cast<const bf16x8*>(&vt[j * 16 + l16][kk * 32 + quad * 8]);
            oa[j] = __builtin_amdgcn_mfma_f32_16x16x32_bf16(ap, bv, oa[j], 0, 0, 0);
        }
    }
    #pragma unroll
    for (int j = 0; j < 4; j++) {
        const int d = j * 16 + l16;
        #pragma unroll
        for (int r = 0; r < 4; r++) {
            const int i = wid * 16 + quad * 4 + r;
            ctx[baseBH + (size_t)(t0 + i) * CH + d] = __float2bfloat16(oa[j][r]);
        }
    }
}

extern "C" void kernel_launch(void* const* d_in, const int* in_sizes, int n_in,
                              void* d_out, int out_size, void* d_ws, size_t ws_size,
                              hipStream_t stream)
{
    const float* query = (const float*)d_in[0];
    const float* key_i = (const float*)d_in[1];
    const float* value = (const float*)d_in[2];
    const float* Wq = (const float*)d_in[3];
    const float* bq = (const float*)d_in[4];
    const float* Wk = (const float*)d_in[5];
    const float* bk = (const float*)d_in[6];
    const float* Wv = (const float*)d_in[7];
    const float* bv = (const float*)d_in[8];
    const float* Wo = (const float*)d_in[9];
    const float* bo = (const float*)d_in[10];
    float* out = (float*)d_out;

    const size_t NELEM = (size_t)MR * CH;   // 16,777,216
    const size_t WELEM = (size_t)CH * CH;   // 1,048,576

    __hip_bfloat16* S0 = (__hip_bfloat16*)d_ws;
    __hip_bfloat16* S1 = S0 + NELEM;
    __hip_bfloat16* S2 = S1 + NELEM;
    __hip_bfloat16* S3 = S2 + NELEM;
    __hip_bfloat16* wqb = S3;
    __hip_bfloat16* wkb = S3 + WELEM;
    __hip_bfloat16* wvb = S3 + 2 * WELEM;
    __hip_bfloat16* wob = S3 + 3 * WELEM;

    __hip_bfloat16* xq = (__hip_bfloat16*)d_out;
    __hip_bfloat16* xk = xq + NELEM;
    __hip_bfloat16* vb = (__hip_bfloat16*)d_out;
    __hip_bfloat16* qb = S1;
    __hip_bfloat16* kb = S2;
    __hip_bfloat16* cb = S0;

    const int nA8 = (int)(NELEM / 8);
    const int nW8 = (int)(WELEM / 8);

    pack_bf16<<<nA8 / 256, 256, 0, stream>>>(query, xq, nA8);
    pack_bf16<<<nA8 / 256, 256, 0, stream>>>(key_i, xk, nA8);
    pack_bf16<<<nA8 / 256, 256, 0, stream>>>(value, S0, nA8);
    pack_bf16<<<nW8 / 256, 256, 0, stream>>>(Wq, wqb, nW8);
    pack_bf16<<<nW8 / 256, 256, 0, stream>>>(Wk, wkb, nW8);
    pack_bf16<<<nW8 / 256, 256, 0, stream>>>(Wv, wvb, nW8);
    pack_bf16<<<nW8 / 256, 256, 0, stream>>>(Wo, wob, nW8);

    dim3 ggrid(CH / 256, MR / 256);         // (4, 64)
    dim3 qkgrid(CH / 256, MR / 256, 2);     // 512 blocks

    gemm_qk256<<<qkgrid, 512, 0, stream>>>(xq, wqb, bq, qb, 0.125f,
                                           xk, wkb, bk, kb);
    gemm_one256<__hip_bfloat16><<<ggrid, 512, 0, stream>>>(S0, wvb, bv, vb);

    attn_kernel<<<BATCH * NH * NBL, 256, 0, stream>>>(qb, kb, vb, cb);

    gemm_one256<float><<<ggrid, 512, 0, stream>>>(cb, wob, bo, out);
}